// Round 1
// baseline (402.360 us; speedup 1.0000x reference)
//
#include <hip/hip_runtime.h>

#define B 64
#define CL 400
#define QL 50
#define HDIM 1024
#define NEG_INF -1e30f

// ---------------- workspace layout (float offsets) ----------------
// qhat : [B][51][H]   q*cqw rows 0..49, c_weight in row 50   (3,342,336)
//        (reused by s2tc [B][QL][H] = 3,276,800 after k_sgemm consumes it)
// qb   : [B][QL]                                             (3,200)
// S    : [B][CL][QL]  raw similarity                         (1,280,000)
// s1   : [B][CL][QL]  softmax over q dim                     (1,280,000)
// s2t  : [B][QL][CL]  softmax over c dim, TRANSPOSED         (1,280,000)
#define QHAT_OFF 0
#define QB_OFF   3342336
#define S_OFF    3345536
#define S1_OFF   4625536
#define S2T_OFF  5905536
// total 7,185,536 floats = 28.7 MB

// ================= K1: qhat = q*cqw (+cw row), qb = q.qw + bias ==========
__global__ __launch_bounds__(256) void k_qprep(
    const float* __restrict__ q, const float* __restrict__ qw,
    const float* __restrict__ cqw, const float* __restrict__ cw,
    const float* __restrict__ bias, float* __restrict__ qhat,
    float* __restrict__ qb)
{
    int b = blockIdx.y;
    int j = blockIdx.x;            // 0..50
    int t = threadIdx.x;           // 256 threads, H = 256*4 exactly
    int h = t * 4;
    float* dst = qhat + ((size_t)b * 51 + j) * HDIM;
    if (j == QL) {
        *(float4*)(dst + h) = *(const float4*)(cw + h);
        return;
    }
    const float* qrow = q + ((size_t)b * QL + j) * HDIM;
    float4 qv  = *(const float4*)(qrow + h);
    float4 cq  = *(const float4*)(cqw + h);
    float4 qwv = *(const float4*)(qw + h);
    float4 o;
    o.x = qv.x * cq.x; o.y = qv.y * cq.y; o.z = qv.z * cq.z; o.w = qv.w * cq.w;
    *(float4*)(dst + h) = o;
    float s = qv.x * qwv.x + qv.y * qwv.y + qv.z * qwv.z + qv.w * qwv.w;
    #pragma unroll
    for (int off = 32; off; off >>= 1) s += __shfl_down(s, off);
    __shared__ float red[4];
    if ((t & 63) == 0) red[t >> 6] = s;
    __syncthreads();
    if (t == 0) qb[b * QL + j] = red[0] + red[1] + red[2] + red[3] + bias[0];
}

// ================= K2: S = c @ qhat^T (K=1024) + fused softmax over j ====
// block: 256 threads (tx 16 x ty 16), tile 64 rows(i) x 64 cols(j, 51 valid)
// thread owns acc[4][4]: i = i0+ty*4+r, j = tx+16*e
#define KC   32
#define LPAD 36   // LDS row stride (words) for [row][k] tiles
__global__ __launch_bounds__(256) void k_sgemm(
    const float* __restrict__ c, const float* __restrict__ qhat,
    const float* __restrict__ qb, const int* __restrict__ qmask,
    float* __restrict__ S, float* __restrict__ s1)
{
    int b  = blockIdx.y;
    int i0 = blockIdx.x * 64;      // 7 tiles cover 400 (+pad)
    int tid = threadIdx.x;
    int tx = tid & 15, ty = tid >> 4;
    int kf = tid & 7, r0 = tid >> 3;

    __shared__ float smem[2 * 64 * LPAD];
    float* cs = smem;               // [64][36]
    float* qs = smem + 64 * LPAD;   // [64][36]

    const float* cb = c + (size_t)b * CL * HDIM;
    const float* qh = qhat + (size_t)b * 51 * HDIM;

    float acc[4][4] = {};
    for (int k0 = 0; k0 < HDIM; k0 += KC) {
        __syncthreads();
        #pragma unroll
        for (int half = 0; half < 2; ++half) {
            int r = r0 + half * 32;
            int gi = i0 + r;
            float4 v = make_float4(0.f, 0.f, 0.f, 0.f);
            if (gi < CL) v = *(const float4*)(cb + (size_t)gi * HDIM + k0 + kf * 4);
            *(float4*)(cs + r * LPAD + kf * 4) = v;
            float4 u = make_float4(0.f, 0.f, 0.f, 0.f);
            if (r < 51) u = *(const float4*)(qh + (size_t)r * HDIM + k0 + kf * 4);
            *(float4*)(qs + r * LPAD + kf * 4) = u;
        }
        __syncthreads();
        #pragma unroll
        for (int kk = 0; kk < KC; kk += 4) {
            float4 av[4], bv[4];
            #pragma unroll
            for (int r = 0; r < 4; ++r)
                av[r] = *(const float4*)(cs + (ty * 4 + r) * LPAD + kk);
            #pragma unroll
            for (int e = 0; e < 4; ++e)
                bv[e] = *(const float4*)(qs + (tx + 16 * e) * LPAD + kk);
            #pragma unroll
            for (int r = 0; r < 4; ++r)
                #pragma unroll
                for (int e = 0; e < 4; ++e)
                    acc[r][e] += av[r].x * bv[e].x + av[r].y * bv[e].y +
                                 av[r].z * bv[e].z + av[r].w * bv[e].w;
        }
    }
    // dump raw tile to LDS (row stride 65 -> conflict-free row reads)
    float* raw = smem;  // 64*65 = 4160 <= 4608
    __syncthreads();
    #pragma unroll
    for (int r = 0; r < 4; ++r)
        #pragma unroll
        for (int e = 0; e < 4; ++e)
            raw[(ty * 4 + r) * 65 + tx + 16 * e] = acc[r][e];
    __syncthreads();
    // softmax over j for 64 rows, one row per thread (tid<64)
    if (tid < 64 && i0 + tid < CL) {
        int i = i0 + tid;
        float* rrow = raw + tid * 65;
        float sc = rrow[50];                    // c_i . c_weight
        const float* qbb = qb + b * QL;
        const int*   qm  = qmask + b * QL;
        float* Srow  = S  + ((size_t)b * CL + i) * QL;
        float* s1row = s1 + ((size_t)b * CL + i) * QL;
        float m = -3.4e38f;
        for (int j = 0; j < QL; ++j) {
            float s = rrow[j] + sc + qbb[j];
            Srow[j] = s;
            float sm = qm[j] ? s : NEG_INF;
            rrow[j] = sm;
            m = fmaxf(m, sm);
        }
        float z = 0.f;
        for (int j = 0; j < QL; ++j) {
            float p = __expf(rrow[j] - m);
            rrow[j] = p; z += p;
        }
        float rz = 1.f / z;
        for (int j = 0; j < QL; ++j) s1row[j] = rrow[j] * rz;
    }
}

// ================= K3: s2t[b][j][i] = softmax_i(S masked by c_mask) ======
__global__ __launch_bounds__(64) void k_s2(
    const float* __restrict__ S, const int* __restrict__ cmask,
    float* __restrict__ s2t)
{
    int b = blockIdx.y, j = blockIdx.x;
    int t = threadIdx.x;
    const float* Sb = S + (size_t)b * CL * QL + j;
    const int*   cm = cmask + b * CL;
    float v[7];
    float m = -3.4e38f;
    #pragma unroll
    for (int k = 0; k < 7; ++k) {
        int i = t + k * 64;
        float s = NEG_INF;
        if (i < CL) s = cm[i] ? Sb[(size_t)i * QL] : NEG_INF;
        v[k] = s;
        m = fmaxf(m, s);
    }
    #pragma unroll
    for (int off = 32; off; off >>= 1) m = fmaxf(m, __shfl_xor(m, off));
    float z = 0.f;
    #pragma unroll
    for (int k = 0; k < 7; ++k) {
        float p = (t + k * 64 < CL) ? __expf(v[k] - m) : 0.f;
        v[k] = p; z += p;
    }
    #pragma unroll
    for (int off = 32; off; off >>= 1) z += __shfl_xor(z, off);
    float rz = 1.f / z;
    float* dst = s2t + ((size_t)b * QL + j) * CL;
    #pragma unroll
    for (int k = 0; k < 7; ++k) {
        int i = t + k * 64;
        if (i < CL) dst[i] = v[k] * rz;
    }
}

// ================= K4: s2tc[b][j][h] = sum_i s2t[j][i] * c[i][h] (K=400) =
// block: 256 threads, tile 64 rows(j, 50 valid) x 64 cols(h)
__global__ __launch_bounds__(256) void k_s2tc(
    const float* __restrict__ s2t, const float* __restrict__ c,
    float* __restrict__ s2tc)
{
    int b  = blockIdx.y;
    int h0 = blockIdx.x * 64;      // 16 tiles
    int tid = threadIdx.x;
    int tx = tid & 15, ty = tid >> 4;
    int kf = tid & 7, r0 = tid >> 3;

    __shared__ float smem[2 * 64 * LPAD];
    float* as = smem;               // [64 j][36]
    float* bs = smem + 64 * LPAD;   // [64 h][36]

    const float* ab = s2t + (size_t)b * QL * CL;
    const float* cb = c   + (size_t)b * CL * HDIM;

    float acc[4][4] = {};
    for (int k0 = 0; k0 < CL; k0 += KC) {
        __syncthreads();
        // stage A: s2t rows j (contiguous along i)
        #pragma unroll
        for (int half = 0; half < 2; ++half) {
            int r = r0 + half * 32;
            int kg = k0 + kf * 4;
            float4 v = make_float4(0.f, 0.f, 0.f, 0.f);
            if (r < QL && kg + 4 <= CL) v = *(const float4*)(ab + (size_t)r * CL + kg);
            *(float4*)(as + r * LPAD + kf * 4) = v;
        }
        // stage B: c rows i=k0+kc, transposed into [h][kc]
        {
            int h4 = tid & 15;
            #pragma unroll
            for (int it = 0; it < 2; ++it) {
                int kc = (tid >> 4) + it * 16;
                int gi = k0 + kc;
                float4 v = make_float4(0.f, 0.f, 0.f, 0.f);
                if (gi < CL) v = *(const float4*)(cb + (size_t)gi * HDIM + h0 + h4 * 4);
                bs[(h4 * 4 + 0) * LPAD + kc] = v.x;
                bs[(h4 * 4 + 1) * LPAD + kc] = v.y;
                bs[(h4 * 4 + 2) * LPAD + kc] = v.z;
                bs[(h4 * 4 + 3) * LPAD + kc] = v.w;
            }
        }
        __syncthreads();
        #pragma unroll
        for (int kk = 0; kk < KC; kk += 4) {
            float4 av[4], bv[4];
            #pragma unroll
            for (int r = 0; r < 4; ++r)
                av[r] = *(const float4*)(as + (ty * 4 + r) * LPAD + kk);
            #pragma unroll
            for (int e = 0; e < 4; ++e)
                bv[e] = *(const float4*)(bs + (tx + 16 * e) * LPAD + kk);
            #pragma unroll
            for (int r = 0; r < 4; ++r)
                #pragma unroll
                for (int e = 0; e < 4; ++e)
                    acc[r][e] += av[r].x * bv[e].x + av[r].y * bv[e].y +
                                 av[r].z * bv[e].z + av[r].w * bv[e].w;
        }
    }
    #pragma unroll
    for (int r = 0; r < 4; ++r) {
        int j = ty * 4 + r;
        if (j < QL)
            #pragma unroll
            for (int e = 0; e < 4; ++e)
                s2tc[((size_t)b * QL + j) * HDIM + h0 + tx + 16 * e] = acc[r][e];
    }
}

// ================= K5: a = s1@q, t = s1@s2tc, out = [c, a, c*a, c*t] =====
// block: 256 threads (tx 16 x ty 16), tile 64 rows(i); h chunks of 64
__global__ __launch_bounds__(256) void k_final(
    const float* __restrict__ c, const float* __restrict__ q,
    const float* __restrict__ s1, const float* __restrict__ s2tc,
    float* __restrict__ out)
{
    int b  = blockIdx.y;
    int i0 = blockIdx.x * 64;      // 7 tiles
    int tid = threadIdx.x;
    int tx = tid & 15, ty = tid >> 4;

    __shared__ float s1s[64 * 52];
    __shared__ float qsm[QL * 68];
    __shared__ float vsm[QL * 68];

    // stage s1 tile [64][50]
    for (int idx = tid; idx < 64 * 52; idx += 256) {
        int r = idx / 52, j = idx - r * 52;
        int gi = i0 + r;
        float v = 0.f;
        if (j < QL && gi < CL) v = s1[((size_t)b * CL + gi) * QL + j];
        s1s[r * 52 + j] = v;
    }

    const float* qb_ = q    + (size_t)b * QL * HDIM;
    const float* vb_ = s2tc + (size_t)b * QL * HDIM;
    const float* cb_ = c    + (size_t)b * CL * HDIM;
    float*       ob_ = out  + (size_t)b * CL * 4 * HDIM;

    int h4 = tid & 15, jr = tid >> 4;
    for (int hc = 0; hc < HDIM / 64; ++hc) {
        int h0 = hc * 64;
        __syncthreads();
        for (int j = jr; j < QL; j += 16) {
            *(float4*)(&qsm[j * 68 + h4 * 4]) = *(const float4*)(qb_ + (size_t)j * HDIM + h0 + h4 * 4);
            *(float4*)(&vsm[j * 68 + h4 * 4]) = *(const float4*)(vb_ + (size_t)j * HDIM + h0 + h4 * 4);
        }
        __syncthreads();
        float a[4][4] = {}, t[4][4] = {};
        #pragma unroll 10
        for (int j = 0; j < QL; ++j) {
            float4 qv = *(const float4*)(&qsm[j * 68 + tx * 4]);
            float4 vv = *(const float4*)(&vsm[j * 68 + tx * 4]);
            #pragma unroll
            for (int r = 0; r < 4; ++r) {
                float w = s1s[(ty * 4 + r) * 52 + j];
                a[r][0] += w * qv.x; a[r][1] += w * qv.y;
                a[r][2] += w * qv.z; a[r][3] += w * qv.w;
                t[r][0] += w * vv.x; t[r][1] += w * vv.y;
                t[r][2] += w * vv.z; t[r][3] += w * vv.w;
            }
        }
        #pragma unroll
        for (int r = 0; r < 4; ++r) {
            int gi = i0 + ty * 4 + r;
            if (gi < CL) {
                float4 cv = *(const float4*)(cb_ + (size_t)gi * HDIM + h0 + tx * 4);
                size_t o = (size_t)gi * (4 * HDIM) + h0 + tx * 4;
                float4 av, cav, tv;
                av.x = a[r][0]; av.y = a[r][1]; av.z = a[r][2]; av.w = a[r][3];
                cav.x = cv.x * av.x; cav.y = cv.y * av.y; cav.z = cv.z * av.z; cav.w = cv.w * av.w;
                tv.x = cv.x * t[r][0]; tv.y = cv.y * t[r][1]; tv.z = cv.z * t[r][2]; tv.w = cv.w * t[r][3];
                *(float4*)(ob_ + o)             = cv;
                *(float4*)(ob_ + o + HDIM)      = av;
                *(float4*)(ob_ + o + 2 * HDIM)  = cav;
                *(float4*)(ob_ + o + 3 * HDIM)  = tv;
            }
        }
    }
}

extern "C" void kernel_launch(void* const* d_in, const int* in_sizes, int n_in,
                              void* d_out, int out_size, void* d_ws, size_t ws_size,
                              hipStream_t stream) {
    const float* c     = (const float*)d_in[0];
    const float* q     = (const float*)d_in[1];
    const int*   cmask = (const int*)d_in[2];
    const int*   qmask = (const int*)d_in[3];
    const float* cw    = (const float*)d_in[4];
    const float* qw    = (const float*)d_in[5];
    const float* cqw   = (const float*)d_in[6];
    const float* bias  = (const float*)d_in[7];
    float* out = (float*)d_out;
    float* ws  = (float*)d_ws;

    float* qhat = ws + QHAT_OFF;
    float* qb   = ws + QB_OFF;
    float* S    = ws + S_OFF;
    float* s1   = ws + S1_OFF;
    float* s2t  = ws + S2T_OFF;
    float* s2tc = ws + QHAT_OFF;   // reuse qhat slot (dead after k_sgemm)

    k_qprep<<<dim3(51, B), 256, 0, stream>>>(q, qw, cqw, cw, bias, qhat, qb);
    k_sgemm<<<dim3(7, B), 256, 0, stream>>>(c, qhat, qb, qmask, S, s1);
    k_s2<<<dim3(QL, B), 64, 0, stream>>>(S, cmask, s2t);
    k_s2tc<<<dim3(16, B), 256, 0, stream>>>(s2t, c, s2tc);
    k_final<<<dim3(7, B), 256, 0, stream>>>(c, q, s1, s2tc, out);
}

// Round 2
// 255.321 us; speedup vs baseline: 1.5759x; 1.5759x over previous
//
#include <hip/hip_runtime.h>

#define B 64
#define CL 400
#define QL 50
#define HDIM 1024
#define NEG_INF -1e30f

typedef __bf16 bf16x8v __attribute__((ext_vector_type(8)));
typedef float f32x4 __attribute__((ext_vector_type(4)));

// ---------------- workspace layout (float offsets) ----------------
#define QHAT_OFF 0
#define QB_OFF   3342336
#define S_OFF    3345536
#define S1_OFF   4625536
#define S2T_OFF  5905536
// total 7,185,536 floats = 28.7 MB

__device__ inline ushort f2bf(float x) {
    uint u = __float_as_uint(x);
    uint r = (u + 0x7FFFu + ((u >> 16) & 1u)) >> 16;
    return (ushort)r;
}
__device__ inline void splitbf(float x, ushort& hi, ushort& lo) {
    ushort h = f2bf(x);
    float hf = __uint_as_float(((uint)h) << 16);
    hi = h;
    lo = f2bf(x - hf);
}

// ================= K1: qhat = q*cqw (+cw row), qb = q.qw + bias ==========
__global__ __launch_bounds__(256) void k_qprep(
    const float* __restrict__ q, const float* __restrict__ qw,
    const float* __restrict__ cqw, const float* __restrict__ cw,
    const float* __restrict__ bias, float* __restrict__ qhat,
    float* __restrict__ qb)
{
    int b = blockIdx.y;
    int j = blockIdx.x;            // 0..50
    int t = threadIdx.x;
    int h = t * 4;
    float* dst = qhat + ((size_t)b * 51 + j) * HDIM;
    if (j == QL) {
        *(float4*)(dst + h) = *(const float4*)(cw + h);
        return;
    }
    const float* qrow = q + ((size_t)b * QL + j) * HDIM;
    float4 qv  = *(const float4*)(qrow + h);
    float4 cq  = *(const float4*)(cqw + h);
    float4 qwv = *(const float4*)(qw + h);
    float4 o;
    o.x = qv.x * cq.x; o.y = qv.y * cq.y; o.z = qv.z * cq.z; o.w = qv.w * cq.w;
    *(float4*)(dst + h) = o;
    float s = qv.x * qwv.x + qv.y * qwv.y + qv.z * qwv.z + qv.w * qwv.w;
    #pragma unroll
    for (int off = 32; off; off >>= 1) s += __shfl_down(s, off);
    __shared__ float red[4];
    if ((t & 63) == 0) red[t >> 6] = s;
    __syncthreads();
    if (t == 0) qb[b * QL + j] = red[0] + red[1] + red[2] + red[3] + bias[0];
}

// ================= K2: S = c @ qhat^T via split-bf16 MFMA + softmax ======
// 256 thr = 4 waves; tile 64(i) x 64(j, 51 valid); K=1024 in chunks of 64.
// Precision: S = hi*hi + hi*lo + lo*hi  (~f32 accurate)
#define ASTR 72   // ushort stride (144 B, 16B-aligned, 2-way banks on b128)
__global__ __launch_bounds__(256) void k_sgemm(
    const float* __restrict__ c, const float* __restrict__ qhat,
    const float* __restrict__ qb, const int* __restrict__ qmask,
    float* __restrict__ S, float* __restrict__ s1)
{
    int b  = blockIdx.y;
    int i0 = blockIdx.x * 64;
    int tid = threadIdx.x;
    int wid = tid >> 6, lane = tid & 63;

    __shared__ __align__(16) ushort smem_u[4 * 64 * ASTR];   // 36,864 B
    ushort* Ahi = smem_u;
    ushort* Alo = smem_u + 1 * 64 * ASTR;
    ushort* Bhi = smem_u + 2 * 64 * ASTR;
    ushort* Blo = smem_u + 3 * 64 * ASTR;
    float*  raw = (float*)smem_u;                            // [64][65] later

    const float* cb = c + (size_t)b * CL * HDIM;
    const float* qh = qhat + (size_t)b * 51 * HDIM;

    int row = tid >> 2;            // 0..63 staging row
    int kq  = (tid & 3) * 16;      // 16 k per thread
    const float* crow = (i0 + row < CL) ? cb + (size_t)(i0 + row) * HDIM : nullptr;
    const float* qrow = (row < 51) ? qh + (size_t)row * HDIM : nullptr;

    int arow = (wid << 4) + (lane & 15);
    int koff = (lane >> 4) << 3;
    int brow = lane & 15;

    f32x4 acc[4] = {};
    for (int k0 = 0; k0 < HDIM; k0 += 64) {
        __syncthreads();
        #pragma unroll
        for (int f = 0; f < 4; ++f) {
            int k = kq + f * 4;
            float4 cv = crow ? *(const float4*)(crow + k0 + k) : make_float4(0.f,0.f,0.f,0.f);
            ushort4 h4, l4;
            splitbf(cv.x, h4.x, l4.x); splitbf(cv.y, h4.y, l4.y);
            splitbf(cv.z, h4.z, l4.z); splitbf(cv.w, h4.w, l4.w);
            *(ushort4*)(&Ahi[row * ASTR + k]) = h4;
            *(ushort4*)(&Alo[row * ASTR + k]) = l4;
            float4 qv = qrow ? *(const float4*)(qrow + k0 + k) : make_float4(0.f,0.f,0.f,0.f);
            splitbf(qv.x, h4.x, l4.x); splitbf(qv.y, h4.y, l4.y);
            splitbf(qv.z, h4.z, l4.z); splitbf(qv.w, h4.w, l4.w);
            *(ushort4*)(&Bhi[row * ASTR + k]) = h4;
            *(ushort4*)(&Blo[row * ASTR + k]) = l4;
        }
        __syncthreads();
        #pragma unroll
        for (int ks = 0; ks < 64; ks += 32) {
            bf16x8v ah = *(const bf16x8v*)(&Ahi[arow * ASTR + koff + ks]);
            bf16x8v al = *(const bf16x8v*)(&Alo[arow * ASTR + koff + ks]);
            #pragma unroll
            for (int jt = 0; jt < 4; ++jt) {
                int bo = (jt * 16 + brow) * ASTR + koff + ks;
                bf16x8v bh = *(const bf16x8v*)(&Bhi[bo]);
                bf16x8v bl = *(const bf16x8v*)(&Blo[bo]);
                acc[jt] = __builtin_amdgcn_mfma_f32_16x16x32_bf16(al, bh, acc[jt], 0, 0, 0);
                acc[jt] = __builtin_amdgcn_mfma_f32_16x16x32_bf16(ah, bl, acc[jt], 0, 0, 0);
                acc[jt] = __builtin_amdgcn_mfma_f32_16x16x32_bf16(ah, bh, acc[jt], 0, 0, 0);
            }
        }
    }
    // frag -> LDS raw[64][65]
    __syncthreads();
    #pragma unroll
    for (int jt = 0; jt < 4; ++jt)
        #pragma unroll
        for (int rg = 0; rg < 4; ++rg)
            raw[((wid << 4) + ((lane >> 4) << 2) + rg) * 65 + jt * 16 + (lane & 15)] = acc[jt][rg];
    __syncthreads();
    // softmax over j for 64 rows, one row per thread
    if (tid < 64 && i0 + tid < CL) {
        int i = i0 + tid;
        float* rrow = raw + tid * 65;
        float sc = rrow[50];                    // c_i . c_weight
        const float* qbb = qb + b * QL;
        const int*   qm  = qmask + b * QL;
        float* Srow  = S  + ((size_t)b * CL + i) * QL;
        float* s1row = s1 + ((size_t)b * CL + i) * QL;
        float m = -3.4e38f;
        for (int j = 0; j < QL; ++j) {
            float s = rrow[j] + sc + qbb[j];
            Srow[j] = s;
            float sm = qm[j] ? s : NEG_INF;
            rrow[j] = sm;
            m = fmaxf(m, sm);
        }
        float z = 0.f;
        for (int j = 0; j < QL; ++j) {
            float p = __expf(rrow[j] - m);
            rrow[j] = p; z += p;
        }
        float rz = 1.f / z;
        for (int j = 0; j < QL; ++j) s1row[j] = rrow[j] * rz;
    }
}

// ================= K3: s2t[b][j][i] = softmax_i(S masked by c_mask) ======
__global__ __launch_bounds__(64) void k_s2(
    const float* __restrict__ S, const int* __restrict__ cmask,
    float* __restrict__ s2t)
{
    int b = blockIdx.y, j = blockIdx.x;
    int t = threadIdx.x;
    const float* Sb = S + (size_t)b * CL * QL + j;
    const int*   cm = cmask + b * CL;
    float v[7];
    float m = -3.4e38f;
    #pragma unroll
    for (int k = 0; k < 7; ++k) {
        int i = t + k * 64;
        float s = NEG_INF;
        if (i < CL) s = cm[i] ? Sb[(size_t)i * QL] : NEG_INF;
        v[k] = s;
        m = fmaxf(m, s);
    }
    #pragma unroll
    for (int off = 32; off; off >>= 1) m = fmaxf(m, __shfl_xor(m, off));
    float z = 0.f;
    #pragma unroll
    for (int k = 0; k < 7; ++k) {
        float p = (t + k * 64 < CL) ? __expf(v[k] - m) : 0.f;
        v[k] = p; z += p;
    }
    #pragma unroll
    for (int off = 32; off; off >>= 1) z += __shfl_xor(z, off);
    float rz = 1.f / z;
    float* dst = s2t + ((size_t)b * QL + j) * CL;
    #pragma unroll
    for (int k = 0; k < 7; ++k) {
        int i = t + k * 64;
        if (i < CL) dst[i] = v[k] * rz;
    }
}

// ================= K4: s2tc = s2t @ c via plain bf16 MFMA (K=400) ========
// tile 64(j, 50 valid) x 64(h); K chunks of 32 (13, zero-padded tail)
#define BSTR 40   // ushort stride (80 B, 16B-aligned, conflict-free b128)
__global__ __launch_bounds__(256) void k_s2tc(
    const float* __restrict__ s2t, const float* __restrict__ c,
    float* __restrict__ s2tc)
{
    int b  = blockIdx.y;
    int h0 = blockIdx.x * 64;
    int tid = threadIdx.x;
    int wid = tid >> 6, lane = tid & 63;

    __shared__ __align__(16) ushort As[64 * BSTR];   // s2 [j][i]
    __shared__ __align__(16) ushort Bs[64 * BSTR];   // c^T [h][i]

    const float* ab = s2t + (size_t)b * QL * CL;
    const float* cb = c   + (size_t)b * CL * HDIM;

    int arw = tid >> 2;            // staging row j
    int akq = (tid & 3) * 8;       // 8 k per thread
    int h4  = tid & 15;
    int kcb = tid >> 4;

    int frow = lane & 15;
    int koff = (lane >> 4) << 3;

    f32x4 acc[4] = {};
    for (int k0 = 0; k0 < 416; k0 += 32) {
        __syncthreads();
        // stage A: s2t rows (j, contiguous i), bf16
        #pragma unroll
        for (int f = 0; f < 2; ++f) {
            int kg = k0 + akq + f * 4;
            float4 v = (arw < QL && kg < CL) ? *(const float4*)(ab + (size_t)arw * CL + kg)
                                             : make_float4(0.f,0.f,0.f,0.f);
            ushort4 p;
            p.x = f2bf(v.x); p.y = f2bf(v.y); p.z = f2bf(v.z); p.w = f2bf(v.w);
            *(ushort4*)(&As[arw * BSTR + akq + f * 4]) = p;
        }
        // stage B: c rows i -> transposed [h][i], bf16
        #pragma unroll
        for (int it = 0; it < 2; ++it) {
            int kc = kcb + it * 16;
            int gi = k0 + kc;
            float4 v = (gi < CL) ? *(const float4*)(cb + (size_t)gi * HDIM + h0 + h4 * 4)
                                 : make_float4(0.f,0.f,0.f,0.f);
            Bs[(h4 * 4 + 0) * BSTR + kc] = f2bf(v.x);
            Bs[(h4 * 4 + 1) * BSTR + kc] = f2bf(v.y);
            Bs[(h4 * 4 + 2) * BSTR + kc] = f2bf(v.z);
            Bs[(h4 * 4 + 3) * BSTR + kc] = f2bf(v.w);
        }
        __syncthreads();
        bf16x8v a = *(const bf16x8v*)(&As[((wid << 4) + frow) * BSTR + koff]);
        #pragma unroll
        for (int ht = 0; ht < 4; ++ht) {
            bf16x8v bb = *(const bf16x8v*)(&Bs[(ht * 16 + frow) * BSTR + koff]);
            acc[ht] = __builtin_amdgcn_mfma_f32_16x16x32_bf16(a, bb, acc[ht], 0, 0, 0);
        }
    }
    #pragma unroll
    for (int ht = 0; ht < 4; ++ht)
        #pragma unroll
        for (int rg = 0; rg < 4; ++rg) {
            int j = (wid << 4) + ((lane >> 4) << 2) + rg;
            if (j < QL)
                s2tc[((size_t)b * QL + j) * HDIM + h0 + ht * 16 + (lane & 15)] = acc[ht][rg];
        }
}

// ================= K5: a = s1@q, t = s1@s2tc, out = [c, a, c*a, c*t] =====
// grid (7 i-tiles, 4 h-quarters, B): each block does 4 h-chunks of 64
__global__ __launch_bounds__(256) void k_final(
    const float* __restrict__ c, const float* __restrict__ q,
    const float* __restrict__ s1, const float* __restrict__ s2tc,
    float* __restrict__ out)
{
    int b  = blockIdx.z;
    int i0 = blockIdx.x * 64;
    int hq = blockIdx.y;
    int tid = threadIdx.x;
    int tx = tid & 15, ty = tid >> 4;

    __shared__ float s1s[64 * 52];
    __shared__ float qsm[QL * 68];
    __shared__ float vsm[QL * 68];

    for (int idx = tid; idx < 64 * 52; idx += 256) {
        int r = idx / 52, j = idx - r * 52;
        int gi = i0 + r;
        float v = 0.f;
        if (j < QL && gi < CL) v = s1[((size_t)b * CL + gi) * QL + j];
        s1s[r * 52 + j] = v;
    }

    const float* qb_ = q    + (size_t)b * QL * HDIM;
    const float* vb_ = s2tc + (size_t)b * QL * HDIM;
    const float* cb_ = c    + (size_t)b * CL * HDIM;
    float*       ob_ = out  + (size_t)b * CL * 4 * HDIM;

    int h4 = tid & 15, jr = tid >> 4;
    for (int hc = hq * 4; hc < hq * 4 + 4; ++hc) {
        int h0 = hc * 64;
        __syncthreads();
        for (int j = jr; j < QL; j += 16) {
            *(float4*)(&qsm[j * 68 + h4 * 4]) = *(const float4*)(qb_ + (size_t)j * HDIM + h0 + h4 * 4);
            *(float4*)(&vsm[j * 68 + h4 * 4]) = *(const float4*)(vb_ + (size_t)j * HDIM + h0 + h4 * 4);
        }
        __syncthreads();
        float a[4][4] = {}, t[4][4] = {};
        #pragma unroll 10
        for (int j = 0; j < QL; ++j) {
            float4 qv = *(const float4*)(&qsm[j * 68 + tx * 4]);
            float4 vv = *(const float4*)(&vsm[j * 68 + tx * 4]);
            #pragma unroll
            for (int r = 0; r < 4; ++r) {
                float w = s1s[(ty * 4 + r) * 52 + j];
                a[r][0] += w * qv.x; a[r][1] += w * qv.y;
                a[r][2] += w * qv.z; a[r][3] += w * qv.w;
                t[r][0] += w * vv.x; t[r][1] += w * vv.y;
                t[r][2] += w * vv.z; t[r][3] += w * vv.w;
            }
        }
        #pragma unroll
        for (int r = 0; r < 4; ++r) {
            int gi = i0 + ty * 4 + r;
            if (gi < CL) {
                float4 cv = *(const float4*)(cb_ + (size_t)gi * HDIM + h0 + tx * 4);
                size_t o = (size_t)gi * (4 * HDIM) + h0 + tx * 4;
                float4 av, cav, tv;
                av.x = a[r][0]; av.y = a[r][1]; av.z = a[r][2]; av.w = a[r][3];
                cav.x = cv.x * av.x; cav.y = cv.y * av.y; cav.z = cv.z * av.z; cav.w = cv.w * av.w;
                tv.x = cv.x * t[r][0]; tv.y = cv.y * t[r][1]; tv.z = cv.z * t[r][2]; tv.w = cv.w * t[r][3];
                *(float4*)(ob_ + o)             = cv;
                *(float4*)(ob_ + o + HDIM)      = av;
                *(float4*)(ob_ + o + 2 * HDIM)  = cav;
                *(float4*)(ob_ + o + 3 * HDIM)  = tv;
            }
        }
    }
}

extern "C" void kernel_launch(void* const* d_in, const int* in_sizes, int n_in,
                              void* d_out, int out_size, void* d_ws, size_t ws_size,
                              hipStream_t stream) {
    const float* c     = (const float*)d_in[0];
    const float* q     = (const float*)d_in[1];
    const int*   cmask = (const int*)d_in[2];
    const int*   qmask = (const int*)d_in[3];
    const float* cw    = (const float*)d_in[4];
    const float* qw    = (const float*)d_in[5];
    const float* cqw   = (const float*)d_in[6];
    const float* bias  = (const float*)d_in[7];
    float* out = (float*)d_out;
    float* ws  = (float*)d_ws;

    float* qhat = ws + QHAT_OFF;
    float* qb   = ws + QB_OFF;
    float* S    = ws + S_OFF;
    float* s1   = ws + S1_OFF;
    float* s2t  = ws + S2T_OFF;
    float* s2tc = ws + QHAT_OFF;   // reuse qhat slot (dead after k_sgemm)

    k_qprep<<<dim3(51, B), 256, 0, stream>>>(q, qw, cqw, cw, bias, qhat, qb);
    k_sgemm<<<dim3(7, B), 256, 0, stream>>>(c, qhat, qb, qmask, S, s1);
    k_s2<<<dim3(QL, B), 64, 0, stream>>>(S, cmask, s2t);
    k_s2tc<<<dim3(16, B), 256, 0, stream>>>(s2t, c, s2tc);
    k_final<<<dim3(7, 4, B), 256, 0, stream>>>(c, q, s1, s2tc, out);
}